// Round 23
// baseline (148.974 us; speedup 1.0000x reference)
//
#include <hip/hip_runtime.h>
#include <math.h>

#define EPS 1e-5f
constexpr int D = 64;
constexpr int BSH = 5;            // bucket shift: 32 nodes per bucket
constexpr int BW = 1 << BSH;      // 32
constexpr int MAXNB = 4096;       // supports N <= 131072
constexpr int EPT = 24;           // edges per thread (fill, 1024-thread blocks)
constexpr int EPT_H = 48;         // edges per thread (hist, 256-thread blocks)
constexpr int CAP = 1024;         // aggregate window capacity (edges)
constexpr int NPB = 32;           // nodes per aggregate block (== BW)

typedef __attribute__((ext_vector_type(8))) short bf16x8;
typedef __attribute__((ext_vector_type(8))) ushort ushort8;
typedef __attribute__((ext_vector_type(4))) float f32x4;

__device__ __forceinline__ ushort f32_to_bf16_rne(float v) {
    unsigned u = __float_as_uint(v);
    return (ushort)((u + 0x7FFFu + ((u >> 16) & 1u)) >> 16);
}
__device__ __forceinline__ float bf16_to_f32(ushort h) {
    return __uint_as_float(((unsigned)h) << 16);
}

// ---- K1: fused prep = hist (blocks [0,hb)) | pack_w ([hb,hb+8)) | xconv ----
__global__ __launch_bounds__(256) void prep_kernel(
        const float* __restrict__ x, ushort* __restrict__ xh, long long M8,
        const int* __restrict__ ei, int* __restrict__ gh, int E, int N, int NB,
        int hb, const float* __restrict__ Wl, const float* __restrict__ Wr,
        ushort* __restrict__ packed) {
    __shared__ int ldsh[MAXNB];
    int bid = blockIdx.x;
    if (bid < hb) {
        for (int t = threadIdx.x; t < NB; t += 256) ldsh[t] = 0;
        __syncthreads();
        int base = bid * (256 * EPT_H);
#pragma unroll
        for (int i = 0; i < EPT_H; ++i) {
            int e = base + threadIdx.x + i * 256;
            if (e < E) {
                int dst = ei[E + e];
                dst = min(max(dst, 0), N - 1);
                atomicAdd(&ldsh[dst >> BSH], 1);
            }
        }
        __syncthreads();
        for (int t = threadIdx.x; t < NB; t += 256) {
            int c = ldsh[t];
            if (c) atomicAdd(&gh[t], c);
        }
    } else if (bid < hb + 8) {
        int t = (bid - hb) * 256 + threadIdx.x;
        int lane = t & 63;
        int frag = t >> 6;
        int kh = frag & 1;
        int ct = (frag >> 1) & 3;
        int hl = (frag >> 3) & 1;
        int mat = (frag >> 4) & 1;
        const float* W = mat ? Wr : Wl;
        int j = (lane & 15) + 16 * ct;
        int d0 = (lane >> 4) * 8 + 32 * kh;
        ushort o[8];
#pragma unroll
        for (int i = 0; i < 8; ++i) {
            float v = W[j * 64 + d0 + i];
            ushort hi = f32_to_bf16_rne(v);
            if (hl == 0) {
                o[i] = hi;
            } else {
                float r = v - __uint_as_float(((unsigned)hi) << 16);
                o[i] = f32_to_bf16_rne(r);
            }
        }
        bf16x8 w;
#pragma unroll
        for (int i = 0; i < 8; ++i) w[i] = (short)o[i];
        *(bf16x8*)&packed[(size_t)t * 8] = w;
    } else {
        long long i = (long long)(bid - hb - 8) * 256 + threadIdx.x;
        if (i < M8) {
            float4 v0 = ((const float4*)x)[i * 2];
            float4 v1 = ((const float4*)x)[i * 2 + 1];
            ushort8 h;
            h[0] = f32_to_bf16_rne(v0.x); h[1] = f32_to_bf16_rne(v0.y);
            h[2] = f32_to_bf16_rne(v0.z); h[3] = f32_to_bf16_rne(v0.w);
            h[4] = f32_to_bf16_rne(v1.x); h[5] = f32_to_bf16_rne(v1.y);
            h[6] = f32_to_bf16_rne(v1.z); h[7] = f32_to_bf16_rne(v1.w);
            *(ushort8*)&xh[i * 8] = h;
        }
    }
}

// ---- B: exclusive scan of bucket counts (NB <= 4096) ----
__global__ __launch_bounds__(1024) void bucket_scan_kernel(
        const int* __restrict__ gh, int* __restrict__ bbase,
        int* __restrict__ gcur, int NB, int E) {
    __shared__ int lds[1024];
    int t = threadIdx.x;
    int v[4];
    int s = 0;
#pragma unroll
    for (int i = 0; i < 4; ++i) {
        int idx = t * 4 + i;
        int d = (idx < NB) ? gh[idx] : 0;
        v[i] = s;
        s += d;
    }
    lds[t] = s;
    __syncthreads();
    for (int off = 1; off < 1024; off <<= 1) {
        int u = (t >= off) ? lds[t - off] : 0;
        __syncthreads();
        lds[t] += u;
        __syncthreads();
    }
    int toff = (t > 0) ? lds[t - 1] : 0;
#pragma unroll
    for (int i = 0; i < 4; ++i) {
        int idx = t * 4 + i;
        if (idx < NB) {
            int bsum = toff + v[i];
            bbase[idx] = bsum;
            gcur[idx] = bsum;
        }
    }
    if (t == 0) bbase[NB] = E;
}

// ---- C: bin edges into bucket-contiguous regions as packed words ----
__global__ __launch_bounds__(1024) void bucket_fill_kernel(
        const int* __restrict__ ei, int* __restrict__ gcur,
        unsigned* __restrict__ pairs, int E, int N, int NB) {
    __shared__ int ldsh[MAXNB];
    for (int t = threadIdx.x; t < NB; t += 1024) ldsh[t] = 0;
    __syncthreads();
    int base = blockIdx.x * (1024 * EPT);
    int lofs[EPT];
#pragma unroll
    for (int i = 0; i < EPT; ++i) {
        int e = base + threadIdx.x + i * 1024;
        if (e < E) {
            int dst = ei[E + e];
            dst = min(max(dst, 0), N - 1);
            lofs[i] = atomicAdd(&ldsh[dst >> BSH], 1);
        }
    }
    __syncthreads();
    for (int t = threadIdx.x; t < NB; t += 1024) {
        int c = ldsh[t];
        int run = c ? atomicAdd(&gcur[t], c) : 0;
        ldsh[t] = run;
    }
    __syncthreads();
#pragma unroll
    for (int i = 0; i < EPT; ++i) {
        int e = base + threadIdx.x + i * 1024;
        if (e < E) {
            int src = ei[e];
            int dst = ei[E + e];
            src = min(max(src, 0), N - 1);
            dst = min(max(dst, 0), N - 1);
            int b = dst >> BSH;
            unsigned w = ((unsigned)src << BSH) | (unsigned)(dst & (BW - 1));
            pairs[ldsh[b] + lofs[i]] = w;
        }
    }
}

// ---- D: per-bucket (32 nodes) sort + register gather -> bf16 mean ----
// 512 threads / 8 waves; wave wv owns nodes wv*4 + k. 4 barriers/window.
__global__ __launch_bounds__(512) void aggregate_kernel(
        const ushort* __restrict__ xh, const unsigned* __restrict__ pairs,
        const int* __restrict__ bbase, ushort* __restrict__ meanh, int N) {
    __shared__ int srcl[CAP];
    __shared__ int cnt[NPB];
    __shared__ int noff[NPB + 1];
    const int b = blockIdx.x;
    const int tid = threadIdx.x;
    const int lane = tid & 63;
    const int wv = tid >> 6;                  // 0..7
    const int slot = lane >> 4;               // 0..3
    const int l16 = lane & 15;
    const int e0 = bbase[b], e1 = bbase[b + 1];
    const int nodebase = b * NPB;

    float4 acc[4];
    int degt[4];
#pragma unroll
    for (int k = 0; k < 4; ++k) {
        acc[k] = make_float4(0.f, 0.f, 0.f, 0.f);
        degt[k] = 0;
    }

    if (tid < NPB) cnt[tid] = 0;
    for (int c0 = e0; c0 < e1; c0 += CAP) {
        const int C = min(CAP, e1 - c0);
        __syncthreads();                      // cnt zeroed, srcl free
        // count per node (global read 1, L2-hot)
        for (int i = tid; i < C; i += 512)
            atomicAdd(&cnt[pairs[c0 + i] & (BW - 1)], 1);
        __syncthreads();
        // exclusive scan of 32 counters (wave 0), rezero cnt in-phase
        if (tid < 64) {
            int c = (lane < NPB) ? cnt[lane] : 0;
            int a = c;
            for (int off = 1; off < NPB; off <<= 1) {
                int u = __shfl_up(a, off, 64);
                if (lane >= off) a += u;
            }
            if (lane < NPB) {
                noff[lane] = a - c;
                cnt[lane] = 0;
            }
            if (lane == NPB - 1) noff[NPB] = a;
        }
        __syncthreads();
        // scatter src into node-sorted LDS order (global read 2, L2-hot)
        for (int i = tid; i < C; i += 512) {
            unsigned w = pairs[c0 + i];
            int lr = (int)(w & (BW - 1));
            int p = noff[lr] + atomicAdd(&cnt[lr], 1);
            srcl[p] = (int)(w >> BSH);
        }
        __syncthreads();
        // rezero cnt for next window (no reader during gather)
        if (tid < NPB) cnt[tid] = 0;
        // gather + accumulate: wave wv owns nodes wv*4 + k
#pragma unroll
        for (int k = 0; k < 4; ++k) {
            int lr = wv * 4 + k;
            int r0 = noff[lr], r1 = noff[lr + 1];
            degt[k] += r1 - r0;
            for (int e = r0 + slot; e < r1; e += 4) {
                int src = srcl[e];
                ushort4 h = *(const ushort4*)&xh[(size_t)src * D + l16 * 4];
                acc[k].x += bf16_to_f32(h.x);
                acc[k].y += bf16_to_f32(h.y);
                acc[k].z += bf16_to_f32(h.z);
                acc[k].w += bf16_to_f32(h.w);
            }
        }
    }
    __syncthreads();
    // slot-reduce, write bf16 mean row to global
#pragma unroll
    for (int k = 0; k < 4; ++k) {
        acc[k].x += __shfl_xor(acc[k].x, 16, 64);
        acc[k].y += __shfl_xor(acc[k].y, 16, 64);
        acc[k].z += __shfl_xor(acc[k].z, 16, 64);
        acc[k].w += __shfl_xor(acc[k].w, 16, 64);
        acc[k].x += __shfl_xor(acc[k].x, 32, 64);
        acc[k].y += __shfl_xor(acc[k].y, 32, 64);
        acc[k].z += __shfl_xor(acc[k].z, 32, 64);
        acc[k].w += __shfl_xor(acc[k].w, 32, 64);
        if (slot == 0) {
            int node = nodebase + wv * 4 + k;
            if (node < N) {
                float inv = 1.0f / fmaxf((float)degt[k], 1.0f);
                ushort4 uv;
                uv.x = f32_to_bf16_rne(acc[k].x * inv);
                uv.y = f32_to_bf16_rne(acc[k].y * inv);
                uv.z = f32_to_bf16_rne(acc[k].z * inv);
                uv.w = f32_to_bf16_rne(acc[k].w * inv);
                *(ushort4*)&meanh[(size_t)node * D + l16 * 4] = uv;
            }
        }
    }
}

// ---- E: lean bf16 MFMA linear; per-block stats partials (NO atomics) ----
__global__ __launch_bounds__(256, 4) void linear_bf16_kernel(
        const ushort* __restrict__ meanh, const ushort* __restrict__ xh,
        const ushort* __restrict__ packed, const float* __restrict__ bl,
        float* __restrict__ out, float* __restrict__ partials, int N) {
    __shared__ float wls[4], wlsq[4];
    const int tid = threadIdx.x;
    const int lane = tid & 63;
    const int wv = tid >> 6;
    const int l16 = lane & 15;
    const int kblk = lane >> 4;
    const int grp = wv & 1;
    const int ctb = (wv >> 1) * 2;
    const int nodebase = blockIdx.x * 32;

    bf16x8 bw[2][2][2];   // [mat][c][kh]
#pragma unroll
    for (int mat = 0; mat < 2; ++mat)
#pragma unroll
        for (int c = 0; c < 2; ++c)
#pragma unroll
            for (int kh = 0; kh < 2; ++kh) {
                int frag = mat * 16 + (ctb + c) * 2 + kh;
                bw[mat][c][kh] =
                    *(const bf16x8*)&packed[((size_t)frag * 64 + lane) * 8];
            }
    float blv[2];
#pragma unroll
    for (int c = 0; c < 2; ++c) blv[c] = bl[(ctb + c) * 16 + l16];

    int arow = min(nodebase + grp * 16 + l16, N - 1);
    bf16x8 am[2], ax[2];
#pragma unroll
    for (int kh = 0; kh < 2; ++kh) {
        am[kh] = *(const bf16x8*)&meanh[(size_t)arow * D + kblk * 8 + kh * 32];
        ax[kh] = *(const bf16x8*)&xh[(size_t)arow * D + kblk * 8 + kh * 32];
    }

    f32x4 oacc[2];
#pragma unroll
    for (int c = 0; c < 2; ++c) oacc[c] = (f32x4)(0.0f);
#pragma unroll
    for (int c = 0; c < 2; ++c)
#pragma unroll
        for (int kh = 0; kh < 2; ++kh) {
            oacc[c] = __builtin_amdgcn_mfma_f32_16x16x32_bf16(
                am[kh], bw[0][c][kh], oacc[c], 0, 0, 0);
            oacc[c] = __builtin_amdgcn_mfma_f32_16x16x32_bf16(
                ax[kh], bw[1][c][kh], oacc[c], 0, 0, 0);
        }

    float ls = 0.0f, lsq = 0.0f;
#pragma unroll
    for (int c = 0; c < 2; ++c) {
#pragma unroll
        for (int r = 0; r < 4; ++r) {
            int row = nodebase + grp * 16 + kblk * 4 + r;
            if (row < N) {
                float v = oacc[c][r] + blv[c];
                out[(size_t)row * D + (ctb + c) * 16 + l16] = v;
                ls += v;
                lsq += v * v;
            }
        }
    }
    for (int off = 32; off > 0; off >>= 1) {
        ls += __shfl_down(ls, off, 64);
        lsq += __shfl_down(lsq, off, 64);
    }
    if (lane == 0) { wls[wv] = ls; wlsq[wv] = lsq; }
    __syncthreads();
    if (tid == 0) {
        partials[(size_t)blockIdx.x * 2]     = wls[0] + wls[1] + wls[2] + wls[3];
        partials[(size_t)blockIdx.x * 2 + 1] = wlsq[0] + wlsq[1] + wlsq[2] + wlsq[3];
    }
}

// ---- F: reduce per-block partials -> stats (single block) ----
__global__ __launch_bounds__(1024) void stats_reduce_kernel(
        const float* __restrict__ partials, float* __restrict__ stats, int n) {
    __shared__ float l0[16], l1[16];
    float s0 = 0.0f, s1 = 0.0f;
    for (int i = threadIdx.x; i < n; i += 1024) {
        s0 += partials[(size_t)i * 2];
        s1 += partials[(size_t)i * 2 + 1];
    }
    for (int off = 32; off > 0; off >>= 1) {
        s0 += __shfl_down(s0, off, 64);
        s1 += __shfl_down(s1, off, 64);
    }
    int wid = threadIdx.x >> 6;
    if ((threadIdx.x & 63) == 0) { l0[wid] = s0; l1[wid] = s1; }
    __syncthreads();
    if (threadIdx.x == 0) {
        float t0 = 0.0f, t1 = 0.0f;
#pragma unroll
        for (int w = 0; w < 16; ++w) { t0 += l0[w]; t1 += l1[w]; }
        stats[0] = t0;
        stats[1] = t1;
    }
}

// ---- in-place graph layernorm on d_out ----
__global__ void norm_kernel(const float* __restrict__ stats,
                            const float* __restrict__ lw,
                            const float* __restrict__ lb,
                            float* out, long long M4) {
    long long i = (long long)blockIdx.x * blockDim.x + threadIdx.x;
    if (i >= M4) return;
    const float inv_M = 1.0f / (float)(M4 * 4);
    float mu = stats[0] * inv_M;
    float var = stats[1] * inv_M - mu * mu;
    float rs = 1.0f / sqrtf(var + EPS);
    float4 v = ((const float4*)out)[i];
    int col = (int)((i * 4) & (D - 1));
    float4 w = *(const float4*)&lw[col];
    float4 b = *(const float4*)&lb[col];
    v.x = (v.x - mu) * rs * w.x + b.x;
    v.y = (v.y - mu) * rs * w.y + b.y;
    v.z = (v.z - mu) * rs * w.z + b.z;
    v.w = (v.w - mu) * rs * w.w + b.w;
    ((float4*)out)[i] = v;
}

extern "C" void kernel_launch(void* const* d_in, const int* in_sizes, int n_in,
                              void* d_out, int out_size, void* d_ws, size_t ws_size,
                              hipStream_t stream) {
    const float* x  = (const float*)d_in[0];
    const int*   ei = (const int*)d_in[1];
    const float* Wl = (const float*)d_in[2];
    const float* bl = (const float*)d_in[3];
    const float* Wr = (const float*)d_in[4];
    const float* lw = (const float*)d_in[5];
    const float* lb = (const float*)d_in[6];
    float* out = (float*)d_out;

    const int N = in_sizes[0] / D;       // 100000
    const int E = in_sizes[1] / 2;       // 1200000
    const int NB = (N + BW - 1) >> BSH;  // 3125
    const int lblocks = (N + 31) / 32;   // 3125

    // ws: stats(2f) | gh(4096) | bbase(4097) | gcur(4096) | pairs(E u32) |
    //     packedw(2048*8 u16) | xh(N*64 u16) | meanh(N*64 u16) | partials
    float* stats    = (float*)d_ws;
    int* gh         = (int*)d_ws + 2;
    int* bbase      = gh + MAXNB;
    int* gcur       = bbase + (MAXNB + 1);
    unsigned* pairs = (unsigned*)(gcur + MAXNB);
    ushort* packedw = (ushort*)(pairs + E);
    ushort* xh      = packedw + 2048 * 8;
    ushort* meanh   = xh + (size_t)N * D;
    float* partials = (float*)(meanh + (size_t)N * D);

    (void)hipMemsetAsync(d_ws, 0, (size_t)(2 + MAXNB) * sizeof(int), stream);

    long long M8 = (long long)N * D / 8;              // 800000
    int hb = (E + 256 * EPT_H - 1) / (256 * EPT_H);   // 98
    int xb = (int)((M8 + 255) / 256);                 // 3125
    prep_kernel<<<hb + 8 + xb, 256, 0, stream>>>(x, xh, M8, ei, gh, E, N, NB,
                                                 hb, Wl, Wr, packedw);

    bucket_scan_kernel<<<1, 1024, 0, stream>>>(gh, bbase, gcur, NB, E);

    int eb = (E + 1024 * EPT - 1) / (1024 * EPT);     // 49
    bucket_fill_kernel<<<eb, 1024, 0, stream>>>(ei, gcur, pairs, E, N, NB);

    aggregate_kernel<<<NB, 512, 0, stream>>>(xh, pairs, bbase, meanh, N);

    linear_bf16_kernel<<<lblocks, 256, 0, stream>>>(meanh, xh, packedw, bl,
                                                    out, partials, N);

    stats_reduce_kernel<<<1, 1024, 0, stream>>>(partials, stats, lblocks);

    long long M4 = (long long)N * D / 4;
    int blocks4 = (int)((M4 + 255) / 256);
    norm_kernel<<<blocks4, 256, 0, stream>>>(stats, lw, lb, out, M4);
}

// Round 24
// 134.161 us; speedup vs baseline: 1.1104x; 1.1104x over previous
//
#include <hip/hip_runtime.h>
#include <math.h>

#define EPS 1e-5f
constexpr int D = 64;
constexpr int BSH = 5;            // bucket shift: 32 nodes per bucket
constexpr int BW = 1 << BSH;      // 32
constexpr int MAXNB = 4096;       // supports N <= 131072
constexpr int EPT = 6;            // edges per thread (fill, 1024-thread blocks)
constexpr int EPT_H = 48;         // edges per thread (hist, 256-thread blocks)
constexpr int CAP = 1024;         // aggregate window capacity (edges)
constexpr int NPB = 32;           // nodes per aggregate block (== BW)

typedef __attribute__((ext_vector_type(8))) short bf16x8;
typedef __attribute__((ext_vector_type(8))) ushort ushort8;
typedef __attribute__((ext_vector_type(4))) float f32x4;

__device__ __forceinline__ ushort f32_to_bf16_rne(float v) {
    unsigned u = __float_as_uint(v);
    return (ushort)((u + 0x7FFFu + ((u >> 16) & 1u)) >> 16);
}
__device__ __forceinline__ float bf16_to_f32(ushort h) {
    return __uint_as_float(((unsigned)h) << 16);
}

// ---- K1: fused prep = hist (blocks [0,hb)) | pack_w ([hb,hb+8)) | xconv ----
__global__ __launch_bounds__(256) void prep_kernel(
        const float* __restrict__ x, ushort* __restrict__ xh, long long M8,
        const int* __restrict__ ei, int* __restrict__ gh, int E, int N, int NB,
        int hb, const float* __restrict__ Wl, const float* __restrict__ Wr,
        ushort* __restrict__ packed) {
    __shared__ int ldsh[MAXNB];
    int bid = blockIdx.x;
    if (bid < hb) {
        for (int t = threadIdx.x; t < NB; t += 256) ldsh[t] = 0;
        __syncthreads();
        int base = bid * (256 * EPT_H);
#pragma unroll
        for (int i = 0; i < EPT_H; ++i) {
            int e = base + threadIdx.x + i * 256;
            if (e < E) {
                int dst = ei[E + e];
                dst = min(max(dst, 0), N - 1);
                atomicAdd(&ldsh[dst >> BSH], 1);
            }
        }
        __syncthreads();
        for (int t = threadIdx.x; t < NB; t += 256) {
            int c = ldsh[t];
            if (c) atomicAdd(&gh[t], c);
        }
    } else if (bid < hb + 8) {
        int t = (bid - hb) * 256 + threadIdx.x;
        int lane = t & 63;
        int frag = t >> 6;
        int kh = frag & 1;
        int ct = (frag >> 1) & 3;
        int hl = (frag >> 3) & 1;
        int mat = (frag >> 4) & 1;
        const float* W = mat ? Wr : Wl;
        int j = (lane & 15) + 16 * ct;
        int d0 = (lane >> 4) * 8 + 32 * kh;
        ushort o[8];
#pragma unroll
        for (int i = 0; i < 8; ++i) {
            float v = W[j * 64 + d0 + i];
            ushort hi = f32_to_bf16_rne(v);
            if (hl == 0) {
                o[i] = hi;
            } else {
                float r = v - __uint_as_float(((unsigned)hi) << 16);
                o[i] = f32_to_bf16_rne(r);
            }
        }
        bf16x8 w;
#pragma unroll
        for (int i = 0; i < 8; ++i) w[i] = (short)o[i];
        *(bf16x8*)&packed[(size_t)t * 8] = w;
    } else {
        long long i = (long long)(bid - hb - 8) * 256 + threadIdx.x;
        if (i < M8) {
            float4 v0 = ((const float4*)x)[i * 2];
            float4 v1 = ((const float4*)x)[i * 2 + 1];
            ushort8 h;
            h[0] = f32_to_bf16_rne(v0.x); h[1] = f32_to_bf16_rne(v0.y);
            h[2] = f32_to_bf16_rne(v0.z); h[3] = f32_to_bf16_rne(v0.w);
            h[4] = f32_to_bf16_rne(v1.x); h[5] = f32_to_bf16_rne(v1.y);
            h[6] = f32_to_bf16_rne(v1.z); h[7] = f32_to_bf16_rne(v1.w);
            *(ushort8*)&xh[i * 8] = h;
        }
    }
}

// ---- B: exclusive scan of bucket counts (NB <= 4096) ----
__global__ __launch_bounds__(1024) void bucket_scan_kernel(
        const int* __restrict__ gh, int* __restrict__ bbase,
        int* __restrict__ gcur, int NB, int E) {
    __shared__ int lds[1024];
    int t = threadIdx.x;
    int v[4];
    int s = 0;
#pragma unroll
    for (int i = 0; i < 4; ++i) {
        int idx = t * 4 + i;
        int d = (idx < NB) ? gh[idx] : 0;
        v[i] = s;
        s += d;
    }
    lds[t] = s;
    __syncthreads();
    for (int off = 1; off < 1024; off <<= 1) {
        int u = (t >= off) ? lds[t - off] : 0;
        __syncthreads();
        lds[t] += u;
        __syncthreads();
    }
    int toff = (t > 0) ? lds[t - 1] : 0;
#pragma unroll
    for (int i = 0; i < 4; ++i) {
        int idx = t * 4 + i;
        if (idx < NB) {
            int bsum = toff + v[i];
            bbase[idx] = bsum;
            gcur[idx] = bsum;
        }
    }
    if (t == 0) bbase[NB] = E;
}

// ---- C: bin edges into bucket-contiguous regions as packed words ----
__global__ __launch_bounds__(1024) void bucket_fill_kernel(
        const int* __restrict__ ei, int* __restrict__ gcur,
        unsigned* __restrict__ pairs, int E, int N, int NB) {
    __shared__ int ldsh[MAXNB];
    for (int t = threadIdx.x; t < NB; t += 1024) ldsh[t] = 0;
    __syncthreads();
    int base = blockIdx.x * (1024 * EPT);
    int lofs[EPT];
#pragma unroll
    for (int i = 0; i < EPT; ++i) {
        int e = base + threadIdx.x + i * 1024;
        if (e < E) {
            int dst = ei[E + e];
            dst = min(max(dst, 0), N - 1);
            lofs[i] = atomicAdd(&ldsh[dst >> BSH], 1);
        }
    }
    __syncthreads();
    for (int t = threadIdx.x; t < NB; t += 1024) {
        int c = ldsh[t];
        int run = c ? atomicAdd(&gcur[t], c) : 0;
        ldsh[t] = run;
    }
    __syncthreads();
#pragma unroll
    for (int i = 0; i < EPT; ++i) {
        int e = base + threadIdx.x + i * 1024;
        if (e < E) {
            int src = ei[e];
            int dst = ei[E + e];
            src = min(max(src, 0), N - 1);
            dst = min(max(dst, 0), N - 1);
            int b = dst >> BSH;
            unsigned w = ((unsigned)src << BSH) | (unsigned)(dst & (BW - 1));
            pairs[ldsh[b] + lofs[i]] = w;
        }
    }
}

// ---- D: per-bucket (32 nodes) sort + register gather -> bf16 mean ----
// 512 threads / 8 waves; wave wv owns nodes wv*4 + k. 4 barriers/window.
__global__ __launch_bounds__(512) void aggregate_kernel(
        const ushort* __restrict__ xh, const unsigned* __restrict__ pairs,
        const int* __restrict__ bbase, ushort* __restrict__ meanh, int N) {
    __shared__ int srcl[CAP];
    __shared__ int cnt[NPB];
    __shared__ int noff[NPB + 1];
    const int b = blockIdx.x;
    const int tid = threadIdx.x;
    const int lane = tid & 63;
    const int wv = tid >> 6;                  // 0..7
    const int slot = lane >> 4;               // 0..3
    const int l16 = lane & 15;
    const int e0 = bbase[b], e1 = bbase[b + 1];
    const int nodebase = b * NPB;

    float4 acc[4];
    int degt[4];
#pragma unroll
    for (int k = 0; k < 4; ++k) {
        acc[k] = make_float4(0.f, 0.f, 0.f, 0.f);
        degt[k] = 0;
    }

    if (tid < NPB) cnt[tid] = 0;
    for (int c0 = e0; c0 < e1; c0 += CAP) {
        const int C = min(CAP, e1 - c0);
        __syncthreads();                      // cnt zeroed, srcl free
        // count per node (global read 1, L2-hot)
        for (int i = tid; i < C; i += 512)
            atomicAdd(&cnt[pairs[c0 + i] & (BW - 1)], 1);
        __syncthreads();
        // exclusive scan of 32 counters (wave 0), rezero cnt in-phase
        if (tid < 64) {
            int c = (lane < NPB) ? cnt[lane] : 0;
            int a = c;
            for (int off = 1; off < NPB; off <<= 1) {
                int u = __shfl_up(a, off, 64);
                if (lane >= off) a += u;
            }
            if (lane < NPB) {
                noff[lane] = a - c;
                cnt[lane] = 0;
            }
            if (lane == NPB - 1) noff[NPB] = a;
        }
        __syncthreads();
        // scatter src into node-sorted LDS order (global read 2, L2-hot)
        for (int i = tid; i < C; i += 512) {
            unsigned w = pairs[c0 + i];
            int lr = (int)(w & (BW - 1));
            int p = noff[lr] + atomicAdd(&cnt[lr], 1);
            srcl[p] = (int)(w >> BSH);
        }
        __syncthreads();
        // rezero cnt for next window (no reader during gather)
        if (tid < NPB) cnt[tid] = 0;
        // gather + accumulate: wave wv owns nodes wv*4 + k
#pragma unroll
        for (int k = 0; k < 4; ++k) {
            int lr = wv * 4 + k;
            int r0 = noff[lr], r1 = noff[lr + 1];
            degt[k] += r1 - r0;
            for (int e = r0 + slot; e < r1; e += 4) {
                int src = srcl[e];
                ushort4 h = *(const ushort4*)&xh[(size_t)src * D + l16 * 4];
                acc[k].x += bf16_to_f32(h.x);
                acc[k].y += bf16_to_f32(h.y);
                acc[k].z += bf16_to_f32(h.z);
                acc[k].w += bf16_to_f32(h.w);
            }
        }
    }
    __syncthreads();
    // slot-reduce, write bf16 mean row to global
#pragma unroll
    for (int k = 0; k < 4; ++k) {
        acc[k].x += __shfl_xor(acc[k].x, 16, 64);
        acc[k].y += __shfl_xor(acc[k].y, 16, 64);
        acc[k].z += __shfl_xor(acc[k].z, 16, 64);
        acc[k].w += __shfl_xor(acc[k].w, 16, 64);
        acc[k].x += __shfl_xor(acc[k].x, 32, 64);
        acc[k].y += __shfl_xor(acc[k].y, 32, 64);
        acc[k].z += __shfl_xor(acc[k].z, 32, 64);
        acc[k].w += __shfl_xor(acc[k].w, 32, 64);
        if (slot == 0) {
            int node = nodebase + wv * 4 + k;
            if (node < N) {
                float inv = 1.0f / fmaxf((float)degt[k], 1.0f);
                ushort4 uv;
                uv.x = f32_to_bf16_rne(acc[k].x * inv);
                uv.y = f32_to_bf16_rne(acc[k].y * inv);
                uv.z = f32_to_bf16_rne(acc[k].z * inv);
                uv.w = f32_to_bf16_rne(acc[k].w * inv);
                *(ushort4*)&meanh[(size_t)node * D + l16 * 4] = uv;
            }
        }
    }
}

// ---- E: lean bf16 MFMA linear; per-block stats partials (NO atomics) ----
__global__ __launch_bounds__(256, 4) void linear_bf16_kernel(
        const ushort* __restrict__ meanh, const ushort* __restrict__ xh,
        const ushort* __restrict__ packed, const float* __restrict__ bl,
        float* __restrict__ out, float* __restrict__ partials, int N) {
    __shared__ float wls[4], wlsq[4];
    const int tid = threadIdx.x;
    const int lane = tid & 63;
    const int wv = tid >> 6;
    const int l16 = lane & 15;
    const int kblk = lane >> 4;
    const int grp = wv & 1;
    const int ctb = (wv >> 1) * 2;
    const int nodebase = blockIdx.x * 32;

    bf16x8 bw[2][2][2];   // [mat][c][kh]
#pragma unroll
    for (int mat = 0; mat < 2; ++mat)
#pragma unroll
        for (int c = 0; c < 2; ++c)
#pragma unroll
            for (int kh = 0; kh < 2; ++kh) {
                int frag = mat * 16 + (ctb + c) * 2 + kh;
                bw[mat][c][kh] =
                    *(const bf16x8*)&packed[((size_t)frag * 64 + lane) * 8];
            }
    float blv[2];
#pragma unroll
    for (int c = 0; c < 2; ++c) blv[c] = bl[(ctb + c) * 16 + l16];

    int arow = min(nodebase + grp * 16 + l16, N - 1);
    bf16x8 am[2], ax[2];
#pragma unroll
    for (int kh = 0; kh < 2; ++kh) {
        am[kh] = *(const bf16x8*)&meanh[(size_t)arow * D + kblk * 8 + kh * 32];
        ax[kh] = *(const bf16x8*)&xh[(size_t)arow * D + kblk * 8 + kh * 32];
    }

    f32x4 oacc[2];
#pragma unroll
    for (int c = 0; c < 2; ++c) oacc[c] = (f32x4)(0.0f);
#pragma unroll
    for (int c = 0; c < 2; ++c)
#pragma unroll
        for (int kh = 0; kh < 2; ++kh) {
            oacc[c] = __builtin_amdgcn_mfma_f32_16x16x32_bf16(
                am[kh], bw[0][c][kh], oacc[c], 0, 0, 0);
            oacc[c] = __builtin_amdgcn_mfma_f32_16x16x32_bf16(
                ax[kh], bw[1][c][kh], oacc[c], 0, 0, 0);
        }

    float ls = 0.0f, lsq = 0.0f;
#pragma unroll
    for (int c = 0; c < 2; ++c) {
#pragma unroll
        for (int r = 0; r < 4; ++r) {
            int row = nodebase + grp * 16 + kblk * 4 + r;
            if (row < N) {
                float v = oacc[c][r] + blv[c];
                out[(size_t)row * D + (ctb + c) * 16 + l16] = v;
                ls += v;
                lsq += v * v;
            }
        }
    }
    for (int off = 32; off > 0; off >>= 1) {
        ls += __shfl_down(ls, off, 64);
        lsq += __shfl_down(lsq, off, 64);
    }
    if (lane == 0) { wls[wv] = ls; wlsq[wv] = lsq; }
    __syncthreads();
    if (tid == 0) {
        partials[(size_t)blockIdx.x * 2]     = wls[0] + wls[1] + wls[2] + wls[3];
        partials[(size_t)blockIdx.x * 2 + 1] = wlsq[0] + wlsq[1] + wlsq[2] + wlsq[3];
    }
}

// ---- F: reduce per-block partials -> stats (single block) ----
__global__ __launch_bounds__(1024) void stats_reduce_kernel(
        const float* __restrict__ partials, float* __restrict__ stats, int n) {
    __shared__ float l0[16], l1[16];
    float s0 = 0.0f, s1 = 0.0f;
    for (int i = threadIdx.x; i < n; i += 1024) {
        s0 += partials[(size_t)i * 2];
        s1 += partials[(size_t)i * 2 + 1];
    }
    for (int off = 32; off > 0; off >>= 1) {
        s0 += __shfl_down(s0, off, 64);
        s1 += __shfl_down(s1, off, 64);
    }
    int wid = threadIdx.x >> 6;
    if ((threadIdx.x & 63) == 0) { l0[wid] = s0; l1[wid] = s1; }
    __syncthreads();
    if (threadIdx.x == 0) {
        float t0 = 0.0f, t1 = 0.0f;
#pragma unroll
        for (int w = 0; w < 16; ++w) { t0 += l0[w]; t1 += l1[w]; }
        stats[0] = t0;
        stats[1] = t1;
    }
}

// ---- in-place graph layernorm on d_out ----
__global__ void norm_kernel(const float* __restrict__ stats,
                            const float* __restrict__ lw,
                            const float* __restrict__ lb,
                            float* out, long long M4) {
    long long i = (long long)blockIdx.x * blockDim.x + threadIdx.x;
    if (i >= M4) return;
    const float inv_M = 1.0f / (float)(M4 * 4);
    float mu = stats[0] * inv_M;
    float var = stats[1] * inv_M - mu * mu;
    float rs = 1.0f / sqrtf(var + EPS);
    float4 v = ((const float4*)out)[i];
    int col = (int)((i * 4) & (D - 1));
    float4 w = *(const float4*)&lw[col];
    float4 b = *(const float4*)&lb[col];
    v.x = (v.x - mu) * rs * w.x + b.x;
    v.y = (v.y - mu) * rs * w.y + b.y;
    v.z = (v.z - mu) * rs * w.z + b.z;
    v.w = (v.w - mu) * rs * w.w + b.w;
    ((float4*)out)[i] = v;
}

extern "C" void kernel_launch(void* const* d_in, const int* in_sizes, int n_in,
                              void* d_out, int out_size, void* d_ws, size_t ws_size,
                              hipStream_t stream) {
    const float* x  = (const float*)d_in[0];
    const int*   ei = (const int*)d_in[1];
    const float* Wl = (const float*)d_in[2];
    const float* bl = (const float*)d_in[3];
    const float* Wr = (const float*)d_in[4];
    const float* lw = (const float*)d_in[5];
    const float* lb = (const float*)d_in[6];
    float* out = (float*)d_out;

    const int N = in_sizes[0] / D;       // 100000
    const int E = in_sizes[1] / 2;       // 1200000
    const int NB = (N + BW - 1) >> BSH;  // 3125
    const int lblocks = (N + 31) / 32;   // 3125

    // ws: stats(2f) | gh(4096) | bbase(4097) | gcur(4096) | pairs(E u32) |
    //     packedw(2048*8 u16) | xh(N*64 u16) | meanh(N*64 u16) | partials
    float* stats    = (float*)d_ws;
    int* gh         = (int*)d_ws + 2;
    int* bbase      = gh + MAXNB;
    int* gcur       = bbase + (MAXNB + 1);
    unsigned* pairs = (unsigned*)(gcur + MAXNB);
    ushort* packedw = (ushort*)(pairs + E);
    ushort* xh      = packedw + 2048 * 8;
    ushort* meanh   = xh + (size_t)N * D;
    float* partials = (float*)(meanh + (size_t)N * D);

    (void)hipMemsetAsync(d_ws, 0, (size_t)(2 + MAXNB) * sizeof(int), stream);

    long long M8 = (long long)N * D / 8;              // 800000
    int hb = (E + 256 * EPT_H - 1) / (256 * EPT_H);   // 98
    int xb = (int)((M8 + 255) / 256);                 // 3125
    prep_kernel<<<hb + 8 + xb, 256, 0, stream>>>(x, xh, M8, ei, gh, E, N, NB,
                                                 hb, Wl, Wr, packedw);

    bucket_scan_kernel<<<1, 1024, 0, stream>>>(gh, bbase, gcur, NB, E);

    int eb = (E + 1024 * EPT - 1) / (1024 * EPT);     // 196
    bucket_fill_kernel<<<eb, 1024, 0, stream>>>(ei, gcur, pairs, E, N, NB);

    aggregate_kernel<<<NB, 512, 0, stream>>>(xh, pairs, bbase, meanh, N);

    linear_bf16_kernel<<<lblocks, 256, 0, stream>>>(meanh, xh, packedw, bl,
                                                    out, partials, N);

    stats_reduce_kernel<<<1, 1024, 0, stream>>>(partials, stats, lblocks);

    long long M4 = (long long)N * D / 4;
    int blocks4 = (int)((M4 + 255) / 256);
    norm_kernel<<<blocks4, 256, 0, stream>>>(stats, lw, lb, out, M4);
}

// Round 25
// 133.336 us; speedup vs baseline: 1.1173x; 1.0062x over previous
//
#include <hip/hip_runtime.h>
#include <math.h>

#define EPS 1e-5f
constexpr int D = 64;
constexpr int BSH = 5;            // bucket shift: 32 nodes per bucket
constexpr int BW = 1 << BSH;      // 32
constexpr int MAXNB = 4096;       // supports N <= 131072
constexpr int EPT = 6;            // edges per thread (fill, 1024-thread blocks)
constexpr int EPT_H = 48;         // edges per thread (hist, 256-thread blocks)
constexpr int CAP = 1024;         // aggregate window capacity (edges)
constexpr int NPB = 32;           // nodes per aggregate block (== BW)

typedef __attribute__((ext_vector_type(8))) short bf16x8;
typedef __attribute__((ext_vector_type(8))) ushort ushort8;
typedef __attribute__((ext_vector_type(4))) float f32x4;

__device__ __forceinline__ ushort f32_to_bf16_rne(float v) {
    unsigned u = __float_as_uint(v);
    return (ushort)((u + 0x7FFFu + ((u >> 16) & 1u)) >> 16);
}
__device__ __forceinline__ float bf16_to_f32(ushort h) {
    return __uint_as_float(((unsigned)h) << 16);
}

// ---- K1: fused prep = hist (blocks [0,hb)) | pack_w ([hb,hb+8)) | xconv ----
__global__ __launch_bounds__(256) void prep_kernel(
        const float* __restrict__ x, ushort* __restrict__ xh, long long M8,
        const int* __restrict__ ei, int* __restrict__ gh, int E, int N, int NB,
        int hb, const float* __restrict__ Wl, const float* __restrict__ Wr,
        ushort* __restrict__ packed) {
    __shared__ int ldsh[MAXNB];
    int bid = blockIdx.x;
    if (bid < hb) {
        for (int t = threadIdx.x; t < NB; t += 256) ldsh[t] = 0;
        __syncthreads();
        int base = bid * (256 * EPT_H);
#pragma unroll
        for (int i = 0; i < EPT_H; ++i) {
            int e = base + threadIdx.x + i * 256;
            if (e < E) {
                int dst = ei[E + e];
                dst = min(max(dst, 0), N - 1);
                atomicAdd(&ldsh[dst >> BSH], 1);
            }
        }
        __syncthreads();
        for (int t = threadIdx.x; t < NB; t += 256) {
            int c = ldsh[t];
            if (c) atomicAdd(&gh[t], c);
        }
    } else if (bid < hb + 8) {
        int t = (bid - hb) * 256 + threadIdx.x;
        int lane = t & 63;
        int frag = t >> 6;
        int kh = frag & 1;
        int ct = (frag >> 1) & 3;
        int hl = (frag >> 3) & 1;
        int mat = (frag >> 4) & 1;
        const float* W = mat ? Wr : Wl;
        int j = (lane & 15) + 16 * ct;
        int d0 = (lane >> 4) * 8 + 32 * kh;
        ushort o[8];
#pragma unroll
        for (int i = 0; i < 8; ++i) {
            float v = W[j * 64 + d0 + i];
            ushort hi = f32_to_bf16_rne(v);
            if (hl == 0) {
                o[i] = hi;
            } else {
                float r = v - __uint_as_float(((unsigned)hi) << 16);
                o[i] = f32_to_bf16_rne(r);
            }
        }
        bf16x8 w;
#pragma unroll
        for (int i = 0; i < 8; ++i) w[i] = (short)o[i];
        *(bf16x8*)&packed[(size_t)t * 8] = w;
    } else {
        long long i = (long long)(bid - hb - 8) * 256 + threadIdx.x;
        if (i < M8) {
            float4 v0 = ((const float4*)x)[i * 2];
            float4 v1 = ((const float4*)x)[i * 2 + 1];
            ushort8 h;
            h[0] = f32_to_bf16_rne(v0.x); h[1] = f32_to_bf16_rne(v0.y);
            h[2] = f32_to_bf16_rne(v0.z); h[3] = f32_to_bf16_rne(v0.w);
            h[4] = f32_to_bf16_rne(v1.x); h[5] = f32_to_bf16_rne(v1.y);
            h[6] = f32_to_bf16_rne(v1.z); h[7] = f32_to_bf16_rne(v1.w);
            *(ushort8*)&xh[i * 8] = h;
        }
    }
}

// ---- B: exclusive scan of bucket counts (NB <= 4096) ----
__global__ __launch_bounds__(1024) void bucket_scan_kernel(
        const int* __restrict__ gh, int* __restrict__ bbase,
        int* __restrict__ gcur, int NB, int E) {
    __shared__ int lds[1024];
    int t = threadIdx.x;
    int v[4];
    int s = 0;
#pragma unroll
    for (int i = 0; i < 4; ++i) {
        int idx = t * 4 + i;
        int d = (idx < NB) ? gh[idx] : 0;
        v[i] = s;
        s += d;
    }
    lds[t] = s;
    __syncthreads();
    for (int off = 1; off < 1024; off <<= 1) {
        int u = (t >= off) ? lds[t - off] : 0;
        __syncthreads();
        lds[t] += u;
        __syncthreads();
    }
    int toff = (t > 0) ? lds[t - 1] : 0;
#pragma unroll
    for (int i = 0; i < 4; ++i) {
        int idx = t * 4 + i;
        if (idx < NB) {
            int bsum = toff + v[i];
            bbase[idx] = bsum;
            gcur[idx] = bsum;
        }
    }
    if (t == 0) bbase[NB] = E;
}

// ---- C: bin edges into bucket-contiguous regions as packed words ----
__global__ __launch_bounds__(1024) void bucket_fill_kernel(
        const int* __restrict__ ei, int* __restrict__ gcur,
        unsigned* __restrict__ pairs, int E, int N, int NB) {
    __shared__ int ldsh[MAXNB];
    for (int t = threadIdx.x; t < NB; t += 1024) ldsh[t] = 0;
    __syncthreads();
    int base = blockIdx.x * (1024 * EPT);
    int lofs[EPT];
#pragma unroll
    for (int i = 0; i < EPT; ++i) {
        int e = base + threadIdx.x + i * 1024;
        if (e < E) {
            int dst = ei[E + e];
            dst = min(max(dst, 0), N - 1);
            lofs[i] = atomicAdd(&ldsh[dst >> BSH], 1);
        }
    }
    __syncthreads();
    for (int t = threadIdx.x; t < NB; t += 1024) {
        int c = ldsh[t];
        int run = c ? atomicAdd(&gcur[t], c) : 0;
        ldsh[t] = run;
    }
    __syncthreads();
#pragma unroll
    for (int i = 0; i < EPT; ++i) {
        int e = base + threadIdx.x + i * 1024;
        if (e < E) {
            int src = ei[e];
            int dst = ei[E + e];
            src = min(max(src, 0), N - 1);
            dst = min(max(dst, 0), N - 1);
            int b = dst >> BSH;
            unsigned w = ((unsigned)src << BSH) | (unsigned)(dst & (BW - 1));
            pairs[ldsh[b] + lofs[i]] = w;
        }
    }
}

// ---- D: per-bucket (32 nodes) sort + register gather -> bf16 mean ----
// 512 threads / 8 waves; wave wv owns nodes wv*4 + k. 4 barriers/window.
__global__ __launch_bounds__(512) void aggregate_kernel(
        const ushort* __restrict__ xh, const unsigned* __restrict__ pairs,
        const int* __restrict__ bbase, ushort* __restrict__ meanh, int N) {
    __shared__ int srcl[CAP];
    __shared__ int cnt[NPB];
    __shared__ int noff[NPB + 1];
    const int b = blockIdx.x;
    const int tid = threadIdx.x;
    const int lane = tid & 63;
    const int wv = tid >> 6;                  // 0..7
    const int slot = lane >> 4;               // 0..3
    const int l16 = lane & 15;
    const int e0 = bbase[b], e1 = bbase[b + 1];
    const int nodebase = b * NPB;

    float4 acc[4];
    int degt[4];
#pragma unroll
    for (int k = 0; k < 4; ++k) {
        acc[k] = make_float4(0.f, 0.f, 0.f, 0.f);
        degt[k] = 0;
    }

    if (tid < NPB) cnt[tid] = 0;
    for (int c0 = e0; c0 < e1; c0 += CAP) {
        const int C = min(CAP, e1 - c0);
        __syncthreads();                      // cnt zeroed, srcl free
        // count per node (global read 1, L2-hot)
        for (int i = tid; i < C; i += 512)
            atomicAdd(&cnt[pairs[c0 + i] & (BW - 1)], 1);
        __syncthreads();
        // exclusive scan of 32 counters (wave 0), rezero cnt in-phase
        if (tid < 64) {
            int c = (lane < NPB) ? cnt[lane] : 0;
            int a = c;
            for (int off = 1; off < NPB; off <<= 1) {
                int u = __shfl_up(a, off, 64);
                if (lane >= off) a += u;
            }
            if (lane < NPB) {
                noff[lane] = a - c;
                cnt[lane] = 0;
            }
            if (lane == NPB - 1) noff[NPB] = a;
        }
        __syncthreads();
        // scatter src into node-sorted LDS order (global read 2, L2-hot)
        for (int i = tid; i < C; i += 512) {
            unsigned w = pairs[c0 + i];
            int lr = (int)(w & (BW - 1));
            int p = noff[lr] + atomicAdd(&cnt[lr], 1);
            srcl[p] = (int)(w >> BSH);
        }
        __syncthreads();
        // rezero cnt for next window (no reader during gather)
        if (tid < NPB) cnt[tid] = 0;
        // gather + accumulate: wave wv owns nodes wv*4 + k
#pragma unroll
        for (int k = 0; k < 4; ++k) {
            int lr = wv * 4 + k;
            int r0 = noff[lr], r1 = noff[lr + 1];
            degt[k] += r1 - r0;
            for (int e = r0 + slot; e < r1; e += 4) {
                int src = srcl[e];
                ushort4 h = *(const ushort4*)&xh[(size_t)src * D + l16 * 4];
                acc[k].x += bf16_to_f32(h.x);
                acc[k].y += bf16_to_f32(h.y);
                acc[k].z += bf16_to_f32(h.z);
                acc[k].w += bf16_to_f32(h.w);
            }
        }
    }
    __syncthreads();
    // slot-reduce, write bf16 mean row to global
#pragma unroll
    for (int k = 0; k < 4; ++k) {
        acc[k].x += __shfl_xor(acc[k].x, 16, 64);
        acc[k].y += __shfl_xor(acc[k].y, 16, 64);
        acc[k].z += __shfl_xor(acc[k].z, 16, 64);
        acc[k].w += __shfl_xor(acc[k].w, 16, 64);
        acc[k].x += __shfl_xor(acc[k].x, 32, 64);
        acc[k].y += __shfl_xor(acc[k].y, 32, 64);
        acc[k].z += __shfl_xor(acc[k].z, 32, 64);
        acc[k].w += __shfl_xor(acc[k].w, 32, 64);
        if (slot == 0) {
            int node = nodebase + wv * 4 + k;
            if (node < N) {
                float inv = 1.0f / fmaxf((float)degt[k], 1.0f);
                ushort4 uv;
                uv.x = f32_to_bf16_rne(acc[k].x * inv);
                uv.y = f32_to_bf16_rne(acc[k].y * inv);
                uv.z = f32_to_bf16_rne(acc[k].z * inv);
                uv.w = f32_to_bf16_rne(acc[k].w * inv);
                *(ushort4*)&meanh[(size_t)node * D + l16 * 4] = uv;
            }
        }
    }
}

// ---- E: lean bf16 MFMA linear; per-block stats partials (NO atomics) ----
__global__ __launch_bounds__(256, 4) void linear_bf16_kernel(
        const ushort* __restrict__ meanh, const ushort* __restrict__ xh,
        const ushort* __restrict__ packed, const float* __restrict__ bl,
        float* __restrict__ out, float* __restrict__ partials, int N) {
    __shared__ float wls[4], wlsq[4];
    const int tid = threadIdx.x;
    const int lane = tid & 63;
    const int wv = tid >> 6;
    const int l16 = lane & 15;
    const int kblk = lane >> 4;
    const int grp = wv & 1;
    const int ctb = (wv >> 1) * 2;
    const int nodebase = blockIdx.x * 32;

    bf16x8 bw[2][2][2];   // [mat][c][kh]
#pragma unroll
    for (int mat = 0; mat < 2; ++mat)
#pragma unroll
        for (int c = 0; c < 2; ++c)
#pragma unroll
            for (int kh = 0; kh < 2; ++kh) {
                int frag = mat * 16 + (ctb + c) * 2 + kh;
                bw[mat][c][kh] =
                    *(const bf16x8*)&packed[((size_t)frag * 64 + lane) * 8];
            }
    float blv[2];
#pragma unroll
    for (int c = 0; c < 2; ++c) blv[c] = bl[(ctb + c) * 16 + l16];

    int arow = min(nodebase + grp * 16 + l16, N - 1);
    bf16x8 am[2], ax[2];
#pragma unroll
    for (int kh = 0; kh < 2; ++kh) {
        am[kh] = *(const bf16x8*)&meanh[(size_t)arow * D + kblk * 8 + kh * 32];
        ax[kh] = *(const bf16x8*)&xh[(size_t)arow * D + kblk * 8 + kh * 32];
    }

    f32x4 oacc[2];
#pragma unroll
    for (int c = 0; c < 2; ++c) oacc[c] = (f32x4)(0.0f);
#pragma unroll
    for (int c = 0; c < 2; ++c)
#pragma unroll
        for (int kh = 0; kh < 2; ++kh) {
            oacc[c] = __builtin_amdgcn_mfma_f32_16x16x32_bf16(
                am[kh], bw[0][c][kh], oacc[c], 0, 0, 0);
            oacc[c] = __builtin_amdgcn_mfma_f32_16x16x32_bf16(
                ax[kh], bw[1][c][kh], oacc[c], 0, 0, 0);
        }

    float ls = 0.0f, lsq = 0.0f;
#pragma unroll
    for (int c = 0; c < 2; ++c) {
#pragma unroll
        for (int r = 0; r < 4; ++r) {
            int row = nodebase + grp * 16 + kblk * 4 + r;
            if (row < N) {
                float v = oacc[c][r] + blv[c];
                out[(size_t)row * D + (ctb + c) * 16 + l16] = v;
                ls += v;
                lsq += v * v;
            }
        }
    }
    for (int off = 32; off > 0; off >>= 1) {
        ls += __shfl_down(ls, off, 64);
        lsq += __shfl_down(lsq, off, 64);
    }
    if (lane == 0) { wls[wv] = ls; wlsq[wv] = lsq; }
    __syncthreads();
    if (tid == 0) {
        partials[(size_t)blockIdx.x * 2]     = wls[0] + wls[1] + wls[2] + wls[3];
        partials[(size_t)blockIdx.x * 2 + 1] = wlsq[0] + wlsq[1] + wlsq[2] + wlsq[3];
    }
}

// ---- F: reduce per-block partials -> stats (single block) ----
__global__ __launch_bounds__(1024) void stats_reduce_kernel(
        const float* __restrict__ partials, float* __restrict__ stats, int n) {
    __shared__ float l0[16], l1[16];
    float s0 = 0.0f, s1 = 0.0f;
    for (int i = threadIdx.x; i < n; i += 1024) {
        s0 += partials[(size_t)i * 2];
        s1 += partials[(size_t)i * 2 + 1];
    }
    for (int off = 32; off > 0; off >>= 1) {
        s0 += __shfl_down(s0, off, 64);
        s1 += __shfl_down(s1, off, 64);
    }
    int wid = threadIdx.x >> 6;
    if ((threadIdx.x & 63) == 0) { l0[wid] = s0; l1[wid] = s1; }
    __syncthreads();
    if (threadIdx.x == 0) {
        float t0 = 0.0f, t1 = 0.0f;
#pragma unroll
        for (int w = 0; w < 16; ++w) { t0 += l0[w]; t1 += l1[w]; }
        stats[0] = t0;
        stats[1] = t1;
    }
}

// ---- in-place graph layernorm on d_out ----
__global__ void norm_kernel(const float* __restrict__ stats,
                            const float* __restrict__ lw,
                            const float* __restrict__ lb,
                            float* out, long long M4) {
    long long i = (long long)blockIdx.x * blockDim.x + threadIdx.x;
    if (i >= M4) return;
    const float inv_M = 1.0f / (float)(M4 * 4);
    float mu = stats[0] * inv_M;
    float var = stats[1] * inv_M - mu * mu;
    float rs = 1.0f / sqrtf(var + EPS);
    float4 v = ((const float4*)out)[i];
    int col = (int)((i * 4) & (D - 1));
    float4 w = *(const float4*)&lw[col];
    float4 b = *(const float4*)&lb[col];
    v.x = (v.x - mu) * rs * w.x + b.x;
    v.y = (v.y - mu) * rs * w.y + b.y;
    v.z = (v.z - mu) * rs * w.z + b.z;
    v.w = (v.w - mu) * rs * w.w + b.w;
    ((float4*)out)[i] = v;
}

extern "C" void kernel_launch(void* const* d_in, const int* in_sizes, int n_in,
                              void* d_out, int out_size, void* d_ws, size_t ws_size,
                              hipStream_t stream) {
    const float* x  = (const float*)d_in[0];
    const int*   ei = (const int*)d_in[1];
    const float* Wl = (const float*)d_in[2];
    const float* bl = (const float*)d_in[3];
    const float* Wr = (const float*)d_in[4];
    const float* lw = (const float*)d_in[5];
    const float* lb = (const float*)d_in[6];
    float* out = (float*)d_out;

    const int N = in_sizes[0] / D;       // 100000
    const int E = in_sizes[1] / 2;       // 1200000
    const int NB = (N + BW - 1) >> BSH;  // 3125
    const int lblocks = (N + 31) / 32;   // 3125

    // ws: stats(2f) | gh(4096) | bbase(4097) | gcur(4096) | pairs(E u32) |
    //     packedw(2048*8 u16) | xh(N*64 u16) | meanh(N*64 u16) | partials
    float* stats    = (float*)d_ws;
    int* gh         = (int*)d_ws + 2;
    int* bbase      = gh + MAXNB;
    int* gcur       = bbase + (MAXNB + 1);
    unsigned* pairs = (unsigned*)(gcur + MAXNB);
    ushort* packedw = (ushort*)(pairs + E);
    ushort* xh      = packedw + 2048 * 8;
    ushort* meanh   = xh + (size_t)N * D;
    float* partials = (float*)(meanh + (size_t)N * D);

    (void)hipMemsetAsync(d_ws, 0, (size_t)(2 + MAXNB) * sizeof(int), stream);

    long long M8 = (long long)N * D / 8;              // 800000
    int hb = (E + 256 * EPT_H - 1) / (256 * EPT_H);   // 98
    int xb = (int)((M8 + 255) / 256);                 // 3125
    prep_kernel<<<hb + 8 + xb, 256, 0, stream>>>(x, xh, M8, ei, gh, E, N, NB,
                                                 hb, Wl, Wr, packedw);

    bucket_scan_kernel<<<1, 1024, 0, stream>>>(gh, bbase, gcur, NB, E);

    int eb = (E + 1024 * EPT - 1) / (1024 * EPT);     // 196
    bucket_fill_kernel<<<eb, 1024, 0, stream>>>(ei, gcur, pairs, E, N, NB);

    aggregate_kernel<<<NB, 512, 0, stream>>>(xh, pairs, bbase, meanh, N);

    linear_bf16_kernel<<<lblocks, 256, 0, stream>>>(meanh, xh, packedw, bl,
                                                    out, partials, N);

    stats_reduce_kernel<<<1, 1024, 0, stream>>>(partials, stats, lblocks);

    long long M4 = (long long)N * D / 4;
    int blocks4 = (int)((M4 + 255) / 256);
    norm_kernel<<<blocks4, 256, 0, stream>>>(stats, lw, lb, out, M4);
}

// Round 26
// 133.126 us; speedup vs baseline: 1.1190x; 1.0016x over previous
//
#include <hip/hip_runtime.h>
#include <math.h>

#define EPS 1e-5f
constexpr int D = 64;
constexpr int BSH = 5;            // bucket shift: 32 nodes per bucket
constexpr int BW = 1 << BSH;      // 32
constexpr int MAXNB = 4096;       // supports N <= 131072
constexpr int EPT = 6;            // edges per thread (fill, 1024-thread blocks)
constexpr int EPT_H = 16;         // edges per thread (hist, 256-thread blocks)
constexpr int CAP = 1024;         // aggregate window capacity (edges)
constexpr int NPB = 32;           // nodes per aggregate block (== BW)

typedef __attribute__((ext_vector_type(8))) short bf16x8;
typedef __attribute__((ext_vector_type(8))) ushort ushort8;
typedef __attribute__((ext_vector_type(4))) float f32x4;

__device__ __forceinline__ ushort f32_to_bf16_rne(float v) {
    unsigned u = __float_as_uint(v);
    return (ushort)((u + 0x7FFFu + ((u >> 16) & 1u)) >> 16);
}
__device__ __forceinline__ float bf16_to_f32(ushort h) {
    return __uint_as_float(((unsigned)h) << 16);
}

// ---- K1: fused prep = hist (blocks [0,hb)) | pack_w ([hb,hb+8)) | xconv ----
__global__ __launch_bounds__(256) void prep_kernel(
        const float* __restrict__ x, ushort* __restrict__ xh, long long M8,
        const int* __restrict__ ei, int* __restrict__ gh, int E, int N, int NB,
        int hb, const float* __restrict__ Wl, const float* __restrict__ Wr,
        ushort* __restrict__ packed) {
    __shared__ int ldsh[MAXNB];
    int bid = blockIdx.x;
    if (bid < hb) {
        for (int t = threadIdx.x; t < NB; t += 256) ldsh[t] = 0;
        __syncthreads();
        int base = bid * (256 * EPT_H);
#pragma unroll
        for (int i = 0; i < EPT_H; ++i) {
            int e = base + threadIdx.x + i * 256;
            if (e < E) {
                int dst = ei[E + e];
                dst = min(max(dst, 0), N - 1);
                atomicAdd(&ldsh[dst >> BSH], 1);
            }
        }
        __syncthreads();
        for (int t = threadIdx.x; t < NB; t += 256) {
            int c = ldsh[t];
            if (c) atomicAdd(&gh[t], c);
        }
    } else if (bid < hb + 8) {
        int t = (bid - hb) * 256 + threadIdx.x;
        int lane = t & 63;
        int frag = t >> 6;
        int kh = frag & 1;
        int ct = (frag >> 1) & 3;
        int hl = (frag >> 3) & 1;
        int mat = (frag >> 4) & 1;
        const float* W = mat ? Wr : Wl;
        int j = (lane & 15) + 16 * ct;
        int d0 = (lane >> 4) * 8 + 32 * kh;
        ushort o[8];
#pragma unroll
        for (int i = 0; i < 8; ++i) {
            float v = W[j * 64 + d0 + i];
            ushort hi = f32_to_bf16_rne(v);
            if (hl == 0) {
                o[i] = hi;
            } else {
                float r = v - __uint_as_float(((unsigned)hi) << 16);
                o[i] = f32_to_bf16_rne(r);
            }
        }
        bf16x8 w;
#pragma unroll
        for (int i = 0; i < 8; ++i) w[i] = (short)o[i];
        *(bf16x8*)&packed[(size_t)t * 8] = w;
    } else {
        long long i = (long long)(bid - hb - 8) * 256 + threadIdx.x;
        if (i < M8) {
            float4 v0 = ((const float4*)x)[i * 2];
            float4 v1 = ((const float4*)x)[i * 2 + 1];
            ushort8 h;
            h[0] = f32_to_bf16_rne(v0.x); h[1] = f32_to_bf16_rne(v0.y);
            h[2] = f32_to_bf16_rne(v0.z); h[3] = f32_to_bf16_rne(v0.w);
            h[4] = f32_to_bf16_rne(v1.x); h[5] = f32_to_bf16_rne(v1.y);
            h[6] = f32_to_bf16_rne(v1.z); h[7] = f32_to_bf16_rne(v1.w);
            *(ushort8*)&xh[i * 8] = h;
        }
    }
}

// ---- B: exclusive scan of bucket counts (NB <= 4096) ----
__global__ __launch_bounds__(1024) void bucket_scan_kernel(
        const int* __restrict__ gh, int* __restrict__ bbase,
        int* __restrict__ gcur, int NB, int E) {
    __shared__ int lds[1024];
    int t = threadIdx.x;
    int v[4];
    int s = 0;
#pragma unroll
    for (int i = 0; i < 4; ++i) {
        int idx = t * 4 + i;
        int d = (idx < NB) ? gh[idx] : 0;
        v[i] = s;
        s += d;
    }
    lds[t] = s;
    __syncthreads();
    for (int off = 1; off < 1024; off <<= 1) {
        int u = (t >= off) ? lds[t - off] : 0;
        __syncthreads();
        lds[t] += u;
        __syncthreads();
    }
    int toff = (t > 0) ? lds[t - 1] : 0;
#pragma unroll
    for (int i = 0; i < 4; ++i) {
        int idx = t * 4 + i;
        if (idx < NB) {
            int bsum = toff + v[i];
            bbase[idx] = bsum;
            gcur[idx] = bsum;
        }
    }
    if (t == 0) bbase[NB] = E;
}

// ---- C: bin edges into bucket-contiguous regions as packed words ----
__global__ __launch_bounds__(1024) void bucket_fill_kernel(
        const int* __restrict__ ei, int* __restrict__ gcur,
        unsigned* __restrict__ pairs, int E, int N, int NB) {
    __shared__ int ldsh[MAXNB];
    for (int t = threadIdx.x; t < NB; t += 1024) ldsh[t] = 0;
    __syncthreads();
    int base = blockIdx.x * (1024 * EPT);
    int lofs[EPT];
#pragma unroll
    for (int i = 0; i < EPT; ++i) {
        int e = base + threadIdx.x + i * 1024;
        if (e < E) {
            int dst = ei[E + e];
            dst = min(max(dst, 0), N - 1);
            lofs[i] = atomicAdd(&ldsh[dst >> BSH], 1);
        }
    }
    __syncthreads();
    for (int t = threadIdx.x; t < NB; t += 1024) {
        int c = ldsh[t];
        int run = c ? atomicAdd(&gcur[t], c) : 0;
        ldsh[t] = run;
    }
    __syncthreads();
#pragma unroll
    for (int i = 0; i < EPT; ++i) {
        int e = base + threadIdx.x + i * 1024;
        if (e < E) {
            int src = ei[e];
            int dst = ei[E + e];
            src = min(max(src, 0), N - 1);
            dst = min(max(dst, 0), N - 1);
            int b = dst >> BSH;
            unsigned w = ((unsigned)src << BSH) | (unsigned)(dst & (BW - 1));
            pairs[ldsh[b] + lofs[i]] = w;
        }
    }
}

// ---- D: per-bucket (32 nodes) sort + register gather -> bf16 mean ----
// 512 threads / 8 waves; wave wv owns nodes wv*4 + k. 4 barriers/window.
__global__ __launch_bounds__(512) void aggregate_kernel(
        const ushort* __restrict__ xh, const unsigned* __restrict__ pairs,
        const int* __restrict__ bbase, ushort* __restrict__ meanh, int N) {
    __shared__ int srcl[CAP];
    __shared__ int cnt[NPB];
    __shared__ int noff[NPB + 1];
    const int b = blockIdx.x;
    const int tid = threadIdx.x;
    const int lane = tid & 63;
    const int wv = tid >> 6;                  // 0..7
    const int slot = lane >> 4;               // 0..3
    const int l16 = lane & 15;
    const int e0 = bbase[b], e1 = bbase[b + 1];
    const int nodebase = b * NPB;

    float4 acc[4];
    int degt[4];
#pragma unroll
    for (int k = 0; k < 4; ++k) {
        acc[k] = make_float4(0.f, 0.f, 0.f, 0.f);
        degt[k] = 0;
    }

    if (tid < NPB) cnt[tid] = 0;
    for (int c0 = e0; c0 < e1; c0 += CAP) {
        const int C = min(CAP, e1 - c0);
        __syncthreads();                      // cnt zeroed, srcl free
        // count per node (global read 1, L2-hot)
        for (int i = tid; i < C; i += 512)
            atomicAdd(&cnt[pairs[c0 + i] & (BW - 1)], 1);
        __syncthreads();
        // exclusive scan of 32 counters (wave 0), rezero cnt in-phase
        if (tid < 64) {
            int c = (lane < NPB) ? cnt[lane] : 0;
            int a = c;
            for (int off = 1; off < NPB; off <<= 1) {
                int u = __shfl_up(a, off, 64);
                if (lane >= off) a += u;
            }
            if (lane < NPB) {
                noff[lane] = a - c;
                cnt[lane] = 0;
            }
            if (lane == NPB - 1) noff[NPB] = a;
        }
        __syncthreads();
        // scatter src into node-sorted LDS order (global read 2, L2-hot)
        for (int i = tid; i < C; i += 512) {
            unsigned w = pairs[c0 + i];
            int lr = (int)(w & (BW - 1));
            int p = noff[lr] + atomicAdd(&cnt[lr], 1);
            srcl[p] = (int)(w >> BSH);
        }
        __syncthreads();
        // rezero cnt for next window (no reader during gather)
        if (tid < NPB) cnt[tid] = 0;
        // gather + accumulate: wave wv owns nodes wv*4 + k
#pragma unroll
        for (int k = 0; k < 4; ++k) {
            int lr = wv * 4 + k;
            int r0 = noff[lr], r1 = noff[lr + 1];
            degt[k] += r1 - r0;
            for (int e = r0 + slot; e < r1; e += 4) {
                int src = srcl[e];
                ushort4 h = *(const ushort4*)&xh[(size_t)src * D + l16 * 4];
                acc[k].x += bf16_to_f32(h.x);
                acc[k].y += bf16_to_f32(h.y);
                acc[k].z += bf16_to_f32(h.z);
                acc[k].w += bf16_to_f32(h.w);
            }
        }
    }
    __syncthreads();
    // slot-reduce, write bf16 mean row to global
#pragma unroll
    for (int k = 0; k < 4; ++k) {
        acc[k].x += __shfl_xor(acc[k].x, 16, 64);
        acc[k].y += __shfl_xor(acc[k].y, 16, 64);
        acc[k].z += __shfl_xor(acc[k].z, 16, 64);
        acc[k].w += __shfl_xor(acc[k].w, 16, 64);
        acc[k].x += __shfl_xor(acc[k].x, 32, 64);
        acc[k].y += __shfl_xor(acc[k].y, 32, 64);
        acc[k].z += __shfl_xor(acc[k].z, 32, 64);
        acc[k].w += __shfl_xor(acc[k].w, 32, 64);
        if (slot == 0) {
            int node = nodebase + wv * 4 + k;
            if (node < N) {
                float inv = 1.0f / fmaxf((float)degt[k], 1.0f);
                ushort4 uv;
                uv.x = f32_to_bf16_rne(acc[k].x * inv);
                uv.y = f32_to_bf16_rne(acc[k].y * inv);
                uv.z = f32_to_bf16_rne(acc[k].z * inv);
                uv.w = f32_to_bf16_rne(acc[k].w * inv);
                *(ushort4*)&meanh[(size_t)node * D + l16 * 4] = uv;
            }
        }
    }
}

// ---- E: lean bf16 MFMA linear; per-block stats partials (NO atomics) ----
__global__ __launch_bounds__(256, 4) void linear_bf16_kernel(
        const ushort* __restrict__ meanh, const ushort* __restrict__ xh,
        const ushort* __restrict__ packed, const float* __restrict__ bl,
        float* __restrict__ out, float* __restrict__ partials, int N) {
    __shared__ float wls[4], wlsq[4];
    const int tid = threadIdx.x;
    const int lane = tid & 63;
    const int wv = tid >> 6;
    const int l16 = lane & 15;
    const int kblk = lane >> 4;
    const int grp = wv & 1;
    const int ctb = (wv >> 1) * 2;
    const int nodebase = blockIdx.x * 32;

    bf16x8 bw[2][2][2];   // [mat][c][kh]
#pragma unroll
    for (int mat = 0; mat < 2; ++mat)
#pragma unroll
        for (int c = 0; c < 2; ++c)
#pragma unroll
            for (int kh = 0; kh < 2; ++kh) {
                int frag = mat * 16 + (ctb + c) * 2 + kh;
                bw[mat][c][kh] =
                    *(const bf16x8*)&packed[((size_t)frag * 64 + lane) * 8];
            }
    float blv[2];
#pragma unroll
    for (int c = 0; c < 2; ++c) blv[c] = bl[(ctb + c) * 16 + l16];

    int arow = min(nodebase + grp * 16 + l16, N - 1);
    bf16x8 am[2], ax[2];
#pragma unroll
    for (int kh = 0; kh < 2; ++kh) {
        am[kh] = *(const bf16x8*)&meanh[(size_t)arow * D + kblk * 8 + kh * 32];
        ax[kh] = *(const bf16x8*)&xh[(size_t)arow * D + kblk * 8 + kh * 32];
    }

    f32x4 oacc[2];
#pragma unroll
    for (int c = 0; c < 2; ++c) oacc[c] = (f32x4)(0.0f);
#pragma unroll
    for (int c = 0; c < 2; ++c)
#pragma unroll
        for (int kh = 0; kh < 2; ++kh) {
            oacc[c] = __builtin_amdgcn_mfma_f32_16x16x32_bf16(
                am[kh], bw[0][c][kh], oacc[c], 0, 0, 0);
            oacc[c] = __builtin_amdgcn_mfma_f32_16x16x32_bf16(
                ax[kh], bw[1][c][kh], oacc[c], 0, 0, 0);
        }

    float ls = 0.0f, lsq = 0.0f;
#pragma unroll
    for (int c = 0; c < 2; ++c) {
#pragma unroll
        for (int r = 0; r < 4; ++r) {
            int row = nodebase + grp * 16 + kblk * 4 + r;
            if (row < N) {
                float v = oacc[c][r] + blv[c];
                out[(size_t)row * D + (ctb + c) * 16 + l16] = v;
                ls += v;
                lsq += v * v;
            }
        }
    }
    for (int off = 32; off > 0; off >>= 1) {
        ls += __shfl_down(ls, off, 64);
        lsq += __shfl_down(lsq, off, 64);
    }
    if (lane == 0) { wls[wv] = ls; wlsq[wv] = lsq; }
    __syncthreads();
    if (tid == 0) {
        partials[(size_t)blockIdx.x * 2]     = wls[0] + wls[1] + wls[2] + wls[3];
        partials[(size_t)blockIdx.x * 2 + 1] = wlsq[0] + wlsq[1] + wlsq[2] + wlsq[3];
    }
}

// ---- F: reduce per-block partials -> stats (single block) ----
__global__ __launch_bounds__(1024) void stats_reduce_kernel(
        const float* __restrict__ partials, float* __restrict__ stats, int n) {
    __shared__ float l0[16], l1[16];
    float s0 = 0.0f, s1 = 0.0f;
    for (int i = threadIdx.x; i < n; i += 1024) {
        s0 += partials[(size_t)i * 2];
        s1 += partials[(size_t)i * 2 + 1];
    }
    for (int off = 32; off > 0; off >>= 1) {
        s0 += __shfl_down(s0, off, 64);
        s1 += __shfl_down(s1, off, 64);
    }
    int wid = threadIdx.x >> 6;
    if ((threadIdx.x & 63) == 0) { l0[wid] = s0; l1[wid] = s1; }
    __syncthreads();
    if (threadIdx.x == 0) {
        float t0 = 0.0f, t1 = 0.0f;
#pragma unroll
        for (int w = 0; w < 16; ++w) { t0 += l0[w]; t1 += l1[w]; }
        stats[0] = t0;
        stats[1] = t1;
    }
}

// ---- in-place graph layernorm on d_out ----
__global__ void norm_kernel(const float* __restrict__ stats,
                            const float* __restrict__ lw,
                            const float* __restrict__ lb,
                            float* out, long long M4) {
    long long i = (long long)blockIdx.x * blockDim.x + threadIdx.x;
    if (i >= M4) return;
    const float inv_M = 1.0f / (float)(M4 * 4);
    float mu = stats[0] * inv_M;
    float var = stats[1] * inv_M - mu * mu;
    float rs = 1.0f / sqrtf(var + EPS);
    float4 v = ((const float4*)out)[i];
    int col = (int)((i * 4) & (D - 1));
    float4 w = *(const float4*)&lw[col];
    float4 b = *(const float4*)&lb[col];
    v.x = (v.x - mu) * rs * w.x + b.x;
    v.y = (v.y - mu) * rs * w.y + b.y;
    v.z = (v.z - mu) * rs * w.z + b.z;
    v.w = (v.w - mu) * rs * w.w + b.w;
    ((float4*)out)[i] = v;
}

extern "C" void kernel_launch(void* const* d_in, const int* in_sizes, int n_in,
                              void* d_out, int out_size, void* d_ws, size_t ws_size,
                              hipStream_t stream) {
    const float* x  = (const float*)d_in[0];
    const int*   ei = (const int*)d_in[1];
    const float* Wl = (const float*)d_in[2];
    const float* bl = (const float*)d_in[3];
    const float* Wr = (const float*)d_in[4];
    const float* lw = (const float*)d_in[5];
    const float* lb = (const float*)d_in[6];
    float* out = (float*)d_out;

    const int N = in_sizes[0] / D;       // 100000
    const int E = in_sizes[1] / 2;       // 1200000
    const int NB = (N + BW - 1) >> BSH;  // 3125
    const int lblocks = (N + 31) / 32;   // 3125

    // ws: stats(2f) | gh(4096) | bbase(4097) | gcur(4096) | pairs(E u32) |
    //     packedw(2048*8 u16) | xh(N*64 u16) | meanh(N*64 u16) | partials
    float* stats    = (float*)d_ws;
    int* gh         = (int*)d_ws + 2;
    int* bbase      = gh + MAXNB;
    int* gcur       = bbase + (MAXNB + 1);
    unsigned* pairs = (unsigned*)(gcur + MAXNB);
    ushort* packedw = (ushort*)(pairs + E);
    ushort* xh      = packedw + 2048 * 8;
    ushort* meanh   = xh + (size_t)N * D;
    float* partials = (float*)(meanh + (size_t)N * D);

    (void)hipMemsetAsync(d_ws, 0, (size_t)(2 + MAXNB) * sizeof(int), stream);

    long long M8 = (long long)N * D / 8;              // 800000
    int hb = (E + 256 * EPT_H - 1) / (256 * EPT_H);   // 293
    int xb = (int)((M8 + 255) / 256);                 // 3125
    prep_kernel<<<hb + 8 + xb, 256, 0, stream>>>(x, xh, M8, ei, gh, E, N, NB,
                                                 hb, Wl, Wr, packedw);

    bucket_scan_kernel<<<1, 1024, 0, stream>>>(gh, bbase, gcur, NB, E);

    int eb = (E + 1024 * EPT - 1) / (1024 * EPT);     // 196
    bucket_fill_kernel<<<eb, 1024, 0, stream>>>(ei, gcur, pairs, E, N, NB);

    aggregate_kernel<<<NB, 512, 0, stream>>>(xh, pairs, bbase, meanh, N);

    linear_bf16_kernel<<<lblocks, 256, 0, stream>>>(meanh, xh, packedw, bl,
                                                    out, partials, N);

    stats_reduce_kernel<<<1, 1024, 0, stream>>>(partials, stats, lblocks);

    long long M4 = (long long)N * D / 4;
    int blocks4 = (int)((M4 + 255) / 256);
    norm_kernel<<<blocks4, 256, 0, stream>>>(stats, lw, lb, out, M4);
}